// Round 7
// baseline (407.198 us; speedup 1.0000x reference)
//
#include <hip/hip_runtime.h>
#include <math.h>

// Problem dims (fixed by the reference)
#define BN    32          // batch
#define TN    512         // TFs
#define GN    2000        // genes
#define PPGN  10          // peaks per gene
#define PN    (GN*PPGN)   // 20000 peaks
#define EN    64000       // edges
#define NOUTN 10          // output channels
#define PQN   (PN/4)      // 5000 p-quads (float4 granules)

#define TCH   16          // number of t-chunks
#define TPC   (TN/TCH)    // 32 t per chunk
#define BH    2           // batch halves
#define BPH   (BN/BH)     // 16 batches per thread

typedef float float4v __attribute__((ext_vector_type(4)));

// Stage 1 (R6 post-mortem): every config since R1 capped at ~4.3-4.6 TB/s on
// the x stream while harness fills hit 6.4 TB/s on the same memory. Single
// common factor: __builtin_nontemporal_load on x (nt cache policy -> L2
// bypass path, lower read throughput). This round: IDENTICAL structure to R6,
// only change = plain cached loads for x. If the cap lifts, nt was the
// culprit; if not, next suspect is the exact 625*64KiB inter-stream stride
// (identical low 16 addr bits across the 16 b-streams).
__global__ __launch_bounds__(320)
void k_perpeak(const float* __restrict__ x,
               const float* __restrict__ W_sub,
               float* __restrict__ partial) {
    int ptile = blockIdx.x;             // 0..15 (fast axis)
    int bh    = blockIdx.y;             // 0..1
    int tc    = blockIdx.z;
    int pq    = ptile * 320 + threadIdx.x;
    if (pq >= PQN) return;              // last ptile: 200/320 active
    int b0 = bh * BPH;
    int t0 = tc * TPC;

    const float4v* xp = (const float4v*)x + ((size_t)b0 * TN + t0) * PQN + pq;
    const float4v* wp = (const float4v*)W_sub + (size_t)t0 * PQN + pq;

    float4v acc[BPH];
#pragma unroll
    for (int j = 0; j < BPH; ++j) acc[j] = (float4v){0.f, 0.f, 0.f, 0.f};

#pragma unroll 1
    for (int t = 0; t < TPC; ++t) {
        float4v wv = wp[(size_t)t * PQN];
#pragma unroll
        for (int j = 0; j < BPH; ++j) {
            float4v xv = xp[((size_t)j * TN + t) * PQN];   // plain cached load
            acc[j] = xv * wv + acc[j];
        }
    }

    float4v* pp = (float4v*)partial + ((size_t)tc * BN + b0) * PQN + pq;
#pragma unroll
    for (int j = 0; j < BPH; ++j)
        __builtin_nontemporal_store(acc[j], pp + (size_t)j * PQN);
}

// Stage 2: h[b,g] = relu(b_sub[g] + sum_tc sum_{k<10} partial[tc][b][g*10+k])
__global__ void k_h(const float* __restrict__ partial,
                    const float* __restrict__ b_sub,
                    float* __restrict__ h) {
    int idx = blockIdx.x * blockDim.x + threadIdx.x;
    if (idx >= BN * GN) return;
    int g = idx % GN, b = idx / GN;
    float s = b_sub[g];
    for (int tc = 0; tc < TCH; ++tc) {
        const float* pp = partial + ((size_t)tc * BN + b) * PN + g * PPGN;
#pragma unroll
        for (int k = 0; k < PPGN; ++k) s += pp[k];
    }
    h[idx] = fmaxf(s, 0.0f);
}

// Stage 3a: degree of target nodes (col)
__global__ void k_deg(const int* __restrict__ col, float* __restrict__ deg) {
    int e = blockIdx.x * blockDim.x + threadIdx.x;
    if (e < EN) atomicAdd(&deg[col[e]], 1.0f);
}

// Stage 3b: dinv = deg^-1/2 (0 where deg == 0)
__global__ void k_dinv(const float* __restrict__ deg, float* __restrict__ dinv) {
    int g = blockIdx.x * blockDim.x + threadIdx.x;
    if (g < GN) {
        float d = deg[g];
        dinv[g] = (d > 0.0f) ? (1.0f / sqrtf(d)) : 0.0f;
    }
}

// Stage 3c: s[b,g] = sum_{e: col[e]==g} dinv[row]*dinv[col] * h[b,row]
// One block per batch; accumulate in LDS (8KB) with LDS atomics, single
// non-atomic writeback.
__global__ __launch_bounds__(256)
void k_s(const int* __restrict__ row, const int* __restrict__ col,
         const float* __restrict__ dinv, const float* __restrict__ h,
         float* __restrict__ s) {
    __shared__ float s_lds[GN];
    int b = blockIdx.x;
    for (int g = threadIdx.x; g < GN; g += 256) s_lds[g] = 0.0f;
    __syncthreads();
    const float* hb = h + (size_t)b * GN;
    for (int e = threadIdx.x; e < EN; e += 256) {
        int r = row[e], c = col[e];
        float nrm = dinv[r] * dinv[c];
        atomicAdd(&s_lds[c], nrm * hb[r]);
    }
    __syncthreads();
    for (int g = threadIdx.x; g < GN; g += 256)
        s[(size_t)b * GN + g] = s_lds[g];
}

// Stage 4: out[b,n] = sum_g sum_c relu(W_gcn[c]*s[b,g]+b_gcn[c]) * W_out[n,2g+c] + b_out[n]
// One wave (64 threads) per (b,n).
__global__ void k_out(const float* __restrict__ s,
                      const float* __restrict__ W_gcn,
                      const float* __restrict__ b_gcn,
                      const float* __restrict__ W_out,
                      const float* __restrict__ b_out,
                      float* __restrict__ out) {
    int b = blockIdx.x / NOUTN;
    int n = blockIdx.x % NOUTN;
    int lane = threadIdx.x;

    float w0 = W_gcn[0], w1 = W_gcn[1];
    float c0 = b_gcn[0], c1 = b_gcn[1];

    float acc = 0.0f;
    for (int g = lane; g < GN; g += 64) {
        float sv = s[(size_t)b * GN + g];
        float g0 = fmaxf(fmaf(sv, w0, c0), 0.0f);
        float g1 = fmaxf(fmaf(sv, w1, c1), 0.0f);
        const float* wo = &W_out[(size_t)n * (GN * 2) + 2 * g];
        acc = fmaf(g0, wo[0], acc);
        acc = fmaf(g1, wo[1], acc);
    }
#pragma unroll
    for (int off = 32; off > 0; off >>= 1)
        acc += __shfl_down(acc, off);
    if (lane == 0) out[b * NOUTN + n] = acc + b_out[n];
}

extern "C" void kernel_launch(void* const* d_in, const int* in_sizes, int n_in,
                              void* d_out, int out_size, void* d_ws, size_t ws_size,
                              hipStream_t stream) {
    const float* x         = (const float*)d_in[0];
    const int*   edge_index= (const int*)  d_in[1];
    const float* W_sub     = (const float*)d_in[2];
    const float* b_sub     = (const float*)d_in[3];
    const float* W_gcn     = (const float*)d_in[4];
    const float* b_gcn     = (const float*)d_in[5];
    const float* W_out     = (const float*)d_in[6];
    const float* b_out     = (const float*)d_in[7];
    float* out = (float*)d_out;

    char* ws = (char*)d_ws;
    // partial: TCH*BN*PN floats = 16*32*20000*4B = 40,960,000 B
    float* partial = (float*)(ws);
    float* h       = (float*)(ws + 40960000);       // B*G floats = 256,000 B
    float* deg     = (float*)(ws + 41216000);       // G   floats =   8,000 B
    float* dinv    = (float*)(ws + 41224000);       // G   floats =   8,000 B
    float* s       = (float*)(ws + 41232000);       // B*G floats = 256,000 B

    const int* row = edge_index;        // edge_index[0,:]
    const int* col = edge_index + EN;   // edge_index[1,:]

    // deg is atomically accumulated -> zero it every call (graph-capture legal)
    hipMemsetAsync(deg, 0, GN * sizeof(float), stream);

    dim3 grid_pp(16, BH, TCH);   // x = p-tile (fast), y = b-half, z = t-chunk
    k_perpeak<<<grid_pp, 320, 0, stream>>>(x, W_sub, partial);
    k_h      <<<((BN * GN) + 255) / 256, 256, 0, stream>>>(partial, b_sub, h);
    k_deg    <<<(EN + 255) / 256,        256, 0, stream>>>(col, deg);
    k_dinv   <<<(GN + 255) / 256,        256, 0, stream>>>(deg, dinv);
    k_s      <<<BN, 256, 0, stream>>>(row, col, dinv, h, s);
    k_out    <<<BN * NOUTN, 64, 0, stream>>>(s, W_gcn, b_gcn, W_out, b_out, out);
}

// Round 8
// 359.497 us; speedup vs baseline: 1.1327x; 1.1327x over previous
//
#include <hip/hip_runtime.h>
#include <math.h>

// Problem dims (fixed by the reference)
#define BN    32          // batch
#define TN    512         // TFs
#define GN    2000        // genes
#define PPGN  10          // peaks per gene
#define PN    (GN*PPGN)   // 20000 peaks
#define EN    64000       // edges
#define NOUTN 10          // output channels
#define PQN   (PN/4)      // 5000 p-quads (float4 granules)

#define TCH   8           // number of t-chunks
#define TPC   (TN/TCH)    // 64 t per chunk
#define BQ    4           // batch quarters
#define BPH   (BN/BQ)     // 8 batches per thread

typedef float float4v __attribute__((ext_vector_type(4)));

// Stage 1 (R7 post-mortem): nt loads are protective (plain loads cost +42us
// via W_sub L2 eviction) -> nt restored. R6's certain-traffic arithmetic
// (1.475GB / ~330us) pins sustained read BW at 4.47 TB/s vs 6.4 TB/s fill
// writes. Suspect: occupancy (R6 ~160+ VGPR -> 8 waves/CU) + per-iter vmcnt
// drain (unroll 1) -> avg in-flight near the latency knee. This round: BPH=8
// (acc 32 + 9-load body ~= 120 VGPR -> 16 waves/CU), unroll 2 (18-load body),
// tc=8, grid 20x4x8=640 blocks (2-3 blocks/CU). W worst-case 164MB
// structural, ~82MB with XCD-L2 pairing ((ptile+4bq)%8: bq{0,2},{1,3} pair).
__global__ __launch_bounds__(256)
void k_perpeak(const float* __restrict__ x,
               const float* __restrict__ W_sub,
               float* __restrict__ partial) {
    int ptile = blockIdx.x;             // 0..19 (fast axis)
    int bq    = blockIdx.y;             // 0..3
    int tc    = blockIdx.z;             // 0..7
    int pq    = ptile * 256 + threadIdx.x;
    if (pq >= PQN) return;              // last ptile: 136/256 active
    int b0 = bq * BPH;
    int t0 = tc * TPC;

    const float4v* xp = (const float4v*)x + ((size_t)b0 * TN + t0) * PQN + pq;
    const float4v* wp = (const float4v*)W_sub + (size_t)t0 * PQN + pq;

    float4v acc[BPH];
#pragma unroll
    for (int j = 0; j < BPH; ++j) acc[j] = (float4v){0.f, 0.f, 0.f, 0.f};

#pragma unroll 2
    for (int t = 0; t < TPC; ++t) {
        float4v wv = wp[(size_t)t * PQN];
#pragma unroll
        for (int j = 0; j < BPH; ++j) {
            float4v xv = __builtin_nontemporal_load(xp + ((size_t)j * TN + t) * PQN);
            acc[j] = xv * wv + acc[j];
        }
    }

    float4v* pp = (float4v*)partial + ((size_t)tc * BN + b0) * PQN + pq;
#pragma unroll
    for (int j = 0; j < BPH; ++j)
        __builtin_nontemporal_store(acc[j], pp + (size_t)j * PQN);
}

// Stage 2: h[b,g] = relu(b_sub[g] + sum_tc sum_{k<10} partial[tc][b][g*10+k])
__global__ void k_h(const float* __restrict__ partial,
                    const float* __restrict__ b_sub,
                    float* __restrict__ h) {
    int idx = blockIdx.x * blockDim.x + threadIdx.x;
    if (idx >= BN * GN) return;
    int g = idx % GN, b = idx / GN;
    float s = b_sub[g];
    for (int tc = 0; tc < TCH; ++tc) {
        const float* pp = partial + ((size_t)tc * BN + b) * PN + g * PPGN;
#pragma unroll
        for (int k = 0; k < PPGN; ++k) s += pp[k];
    }
    h[idx] = fmaxf(s, 0.0f);
}

// Stage 3a: degree of target nodes (col)
__global__ void k_deg(const int* __restrict__ col, float* __restrict__ deg) {
    int e = blockIdx.x * blockDim.x + threadIdx.x;
    if (e < EN) atomicAdd(&deg[col[e]], 1.0f);
}

// Stage 3b: dinv = deg^-1/2 (0 where deg == 0)
__global__ void k_dinv(const float* __restrict__ deg, float* __restrict__ dinv) {
    int g = blockIdx.x * blockDim.x + threadIdx.x;
    if (g < GN) {
        float d = deg[g];
        dinv[g] = (d > 0.0f) ? (1.0f / sqrtf(d)) : 0.0f;
    }
}

// Stage 3c: s[b,g] = sum_{e: col[e]==g} dinv[row]*dinv[col] * h[b,row]
// One block per batch; accumulate in LDS (8KB) with LDS atomics, single
// non-atomic writeback.
__global__ __launch_bounds__(256)
void k_s(const int* __restrict__ row, const int* __restrict__ col,
         const float* __restrict__ dinv, const float* __restrict__ h,
         float* __restrict__ s) {
    __shared__ float s_lds[GN];
    int b = blockIdx.x;
    for (int g = threadIdx.x; g < GN; g += 256) s_lds[g] = 0.0f;
    __syncthreads();
    const float* hb = h + (size_t)b * GN;
    for (int e = threadIdx.x; e < EN; e += 256) {
        int r = row[e], c = col[e];
        float nrm = dinv[r] * dinv[c];
        atomicAdd(&s_lds[c], nrm * hb[r]);
    }
    __syncthreads();
    for (int g = threadIdx.x; g < GN; g += 256)
        s[(size_t)b * GN + g] = s_lds[g];
}

// Stage 4: out[b,n] = sum_g sum_c relu(W_gcn[c]*s[b,g]+b_gcn[c]) * W_out[n,2g+c] + b_out[n]
// One wave (64 threads) per (b,n).
__global__ void k_out(const float* __restrict__ s,
                      const float* __restrict__ W_gcn,
                      const float* __restrict__ b_gcn,
                      const float* __restrict__ W_out,
                      const float* __restrict__ b_out,
                      float* __restrict__ out) {
    int b = blockIdx.x / NOUTN;
    int n = blockIdx.x % NOUTN;
    int lane = threadIdx.x;

    float w0 = W_gcn[0], w1 = W_gcn[1];
    float c0 = b_gcn[0], c1 = b_gcn[1];

    float acc = 0.0f;
    for (int g = lane; g < GN; g += 64) {
        float sv = s[(size_t)b * GN + g];
        float g0 = fmaxf(fmaf(sv, w0, c0), 0.0f);
        float g1 = fmaxf(fmaf(sv, w1, c1), 0.0f);
        const float* wo = &W_out[(size_t)n * (GN * 2) + 2 * g];
        acc = fmaf(g0, wo[0], acc);
        acc = fmaf(g1, wo[1], acc);
    }
#pragma unroll
    for (int off = 32; off > 0; off >>= 1)
        acc += __shfl_down(acc, off);
    if (lane == 0) out[b * NOUTN + n] = acc + b_out[n];
}

extern "C" void kernel_launch(void* const* d_in, const int* in_sizes, int n_in,
                              void* d_out, int out_size, void* d_ws, size_t ws_size,
                              hipStream_t stream) {
    const float* x         = (const float*)d_in[0];
    const int*   edge_index= (const int*)  d_in[1];
    const float* W_sub     = (const float*)d_in[2];
    const float* b_sub     = (const float*)d_in[3];
    const float* W_gcn     = (const float*)d_in[4];
    const float* b_gcn     = (const float*)d_in[5];
    const float* W_out     = (const float*)d_in[6];
    const float* b_out     = (const float*)d_in[7];
    float* out = (float*)d_out;

    char* ws = (char*)d_ws;
    // partial: TCH*BN*PN floats = 8*32*20000*4B = 20,480,000 B
    float* partial = (float*)(ws);
    float* h       = (float*)(ws + 20480000);       // B*G floats = 256,000 B
    float* deg     = (float*)(ws + 20736000);       // G   floats =   8,000 B
    float* dinv    = (float*)(ws + 20744000);       // G   floats =   8,000 B
    float* s       = (float*)(ws + 20752000);       // B*G floats = 256,000 B

    const int* row = edge_index;        // edge_index[0,:]
    const int* col = edge_index + EN;   // edge_index[1,:]

    // deg is atomically accumulated -> zero it every call (graph-capture legal)
    hipMemsetAsync(deg, 0, GN * sizeof(float), stream);

    dim3 grid_pp(20, BQ, TCH);   // x = p-tile (fast), y = b-quarter, z = t-chunk
    k_perpeak<<<grid_pp, 256, 0, stream>>>(x, W_sub, partial);
    k_h      <<<((BN * GN) + 255) / 256, 256, 0, stream>>>(partial, b_sub, h);
    k_deg    <<<(EN + 255) / 256,        256, 0, stream>>>(col, deg);
    k_dinv   <<<(GN + 255) / 256,        256, 0, stream>>>(deg, dinv);
    k_s      <<<BN, 256, 0, stream>>>(row, col, dinv, h, s);
    k_out    <<<BN * NOUTN, 64, 0, stream>>>(s, W_gcn, b_gcn, W_out, b_out, out);
}